// Round 15
// baseline (56.396 us; speedup 1.0000x reference)
//
#include <hip/hip_runtime.h>
#include <math.h>

// PseudoGroupContrast — qt-in-LDS, register act/ema, high-TLP design.
//
//   prep:   queue fp32 -> fp8 e4m3, MFMA-fragment-tiled, in d_ws (48 KB).
//   prepQ:  per-class queue sums (fp8) into pad rows 375..377 (tile 23,
//           lr=7..9); rows 378..383 zero.
//   main:   grid B/128, block 512 (8 waves), LDS 48 KB -> 3 blocks/CU,
//           launch_bounds(512,6) -> ~24 waves/CU. Per block:
//             - 6 glds/thread stage qt -> LDS (fire-and-forget)
//             - per wave: 8 act float4 reg loads -> ssa -> af fp8 pack;
//               8 ema loads -> sse,dae -> def2; mask/plab issued early
//             - one __syncthreads (auto vmcnt drain) -> qt ready
//             - 24-tile loop: 4 ds_read_b64 (conflict-free) + 4 fp8 MFMA
//               + 4 __expf;  tile 23: lr<7 -> S1, lanes 7..9 carry S2/class
//           per = log(exp(def2)+S1) - (S2+def2)/126,  def2 = 2*f_hat.ef_hat
//   finish: deterministic reduce of 1024 block partials -> out.

#define D       128
#define NQ      375
#define QS      125
#define INV126  (1.0f/126.0f)
#define QT_BYTES 49152

typedef __attribute__((ext_vector_type(4))) float f32x4;

#if defined(__has_builtin)
#if __has_builtin(__builtin_amdgcn_cvt_pk_fp8_f32)
#define HAVE_CVT_FP8 1
#endif
#endif

#ifndef HAVE_CVT_FP8
static __device__ __forceinline__ unsigned f2e4m3_sw(float x) {
    unsigned u = __float_as_uint(x);
    unsigned s = (u >> 24) & 0x80;
    int e = (int)((u >> 23) & 0xFF);
    unsigned m = u & 0x7FFFFF;
    if (e == 0) return s;
    int te = e - 120;
    unsigned val;
    if (te >= 1) {
        unsigned keep = m >> 20;
        unsigned rest = m & 0xFFFFF;
        keep += (rest > 0x80000) || (rest == 0x80000 && (keep & 1));
        if (keep == 8) { keep = 0; te += 1; }
        val = (te >= 16) ? 0x7E : ((unsigned)(te << 3) | keep);
    } else {
        unsigned full = m | 0x800000;
        int sh = 21 - te;
        if (sh > 31) val = 0;
        else {
            unsigned keep = full >> sh;
            unsigned rem = full & ((1u << sh) - 1);
            unsigned half = 1u << (sh - 1);
            keep += (rem > half) || (rem == half && (keep & 1));
            val = keep;
        }
    }
    return s | val;
}
#endif

static __device__ __forceinline__ unsigned pk4(float4 v) {
#ifdef HAVE_CVT_FP8
    int r = __builtin_amdgcn_cvt_pk_fp8_f32(v.x, v.y, 0, false);
    r = __builtin_amdgcn_cvt_pk_fp8_f32(v.z, v.w, r, true);
    return (unsigned)r;
#else
    return f2e4m3_sw(v.x) | (f2e4m3_sw(v.y) << 8)
         | (f2e4m3_sw(v.z) << 16) | (f2e4m3_sw(v.w) << 24);
#endif
}

static __device__ __forceinline__ unsigned char pk1(float x) {
#ifdef HAVE_CVT_FP8
    return (unsigned char)(__builtin_amdgcn_cvt_pk_fp8_f32(x, x, 0, false) & 0xff);
#else
    return (unsigned char)f2e4m3_sw(x);
#endif
}

static __device__ __forceinline__ long pk8(float gs, float4 a, float4 b) {
    float4 sa = make_float4(gs * a.x, gs * a.y, gs * a.z, gs * a.w);
    float4 sb = make_float4(gs * b.x, gs * b.y, gs * b.z, gs * b.w);
    unsigned lo = pk4(sa), hi = pk4(sb);
    return (long)(((unsigned long)hi << 32) | (unsigned long)lo);
}

static __device__ __forceinline__ void glds16(const void* g, void* l) {
    __builtin_amdgcn_global_load_lds(
        (const __attribute__((address_space(1))) void*)g,
        (__attribute__((address_space(3))) void*)l, 16, 0, 0);
}

// ---- prep: queue -> fp8, fragment-tiled (rows >= 375 zeroed) ----
__global__ void pgc_prep(const float* __restrict__ queue,
                         unsigned long long* __restrict__ qt)
{
    int u = blockIdx.x * 256 + threadIdx.x;      // 0..6143
    if (u >= 6144) return;
    int l = u & 63, ks = (u >> 6) & 3, nt = u >> 8;
    int row = nt * 16 + (l & 15);
    int k0 = (l >> 4) * 32 + ks * 8;
    float4 a = make_float4(0.f, 0.f, 0.f, 0.f);
    float4 b = make_float4(0.f, 0.f, 0.f, 0.f);
    if (row < NQ) {
        const float* p = queue + row * D + k0;
        a = *(const float4*)p;
        b = *(const float4*)(p + 4);
    }
    unsigned lo = pk4(a), hi = pk4(b);
    qt[u] = ((unsigned long long)hi << 32) | (unsigned long long)lo;
}

// ---- prepQ: class sums into pad rows 375..377 ----
__global__ void pgc_prep_qsum(const float* __restrict__ queue,
                              unsigned char* __restrict__ qtb)
{
    int c = blockIdx.x;          // 0..2
    int d = threadIdx.x;         // 0..127
    float s = 0.f;
    const float* p = queue + (long)c * QS * D + d;
    for (int r = 0; r < QS; ++r) s += p[r * D];
    int lg = d >> 5, ks = (d >> 3) & 3, j = d & 7;
    int u = 23 * 256 + ks * 64 + lg * 16 + 7 + c;    // tile 23, lr = 7+c
    qtb[u * 8 + j] = pk1(s);
}

// ---- main ----
__global__ __launch_bounds__(512, 6) void pgc_main(
    const float* __restrict__ act,
    const float* __restrict__ ema,
    const float* __restrict__ plab,
    const float* __restrict__ mask,
    const unsigned long long* __restrict__ qt,
    float* __restrict__ partial,
    int B)
{
    __shared__ unsigned long long qt_lds[6144];      // 49152 B
    __shared__ float s_red[8];

    const int tid = threadIdx.x;
    const int w   = tid >> 6;      // 0..7
    const int l   = tid & 63;
    const int lr  = l & 15;        // own sample row / C col
    const int seg = l >> 4;        // k-segment / C row group
    const long rowbase = (long)blockIdx.x * 128 + w * 16;

    // ---- 1) stage qt -> LDS: 6 glds/thread, fire-and-forget ----
    #pragma unroll
    for (int i = 0; i < 6; ++i) {
        // instr i, wave w writes LDS bytes [i*8192 + w*1024, +1024)
        glds16((const char*)qt + i * 8192 + w * 1024 + l * 16,
               (char*)qt_lds + i * 8192 + w * 1024);
    }

    // ---- 2) act: 8 independent float4 reg loads ----
    long grow = rowbase + lr;
    const bool valid = grow < (long)B;
    const long gr = valid ? grow : (long)B - 1;

    const float4* ap = (const float4*)(act + gr * D) + seg * 8;
    float4 av[8];
    #pragma unroll
    for (int i = 0; i < 8; ++i) av[i] = ap[i];

    float ssa = 0.f;
    #pragma unroll
    for (int i = 0; i < 8; ++i)
        ssa += av[i].x*av[i].x + av[i].y*av[i].y + av[i].z*av[i].z + av[i].w*av[i].w;
    ssa += __shfl_xor(ssa, 16); ssa += __shfl_xor(ssa, 32);
    const float inva = 1.0f / fmaxf(sqrtf(ssa), 1e-12f);
    const float gs   = 2.0f * inva;                  // fold 1/T + norm into A

    long af[4];
    #pragma unroll
    for (int ks = 0; ks < 4; ++ks)                   // k = seg*32 + ks*8 ..
        af[ks] = pk8(gs, av[2 * ks], av[2 * ks + 1]);

    // ---- 3) ema: 8 loads -> sse, dae -> def2 ----
    const float4* ep = (const float4*)(ema + gr * D) + seg * 8;
    float4 ev[8];
    #pragma unroll
    for (int i = 0; i < 8; ++i) ev[i] = ep[i];

    float sse = 0.f, dae = 0.f;
    #pragma unroll
    for (int i = 0; i < 8; ++i) {
        sse += ev[i].x*ev[i].x + ev[i].y*ev[i].y + ev[i].z*ev[i].z + ev[i].w*ev[i].w;
        dae += av[i].x*ev[i].x + av[i].y*ev[i].y + av[i].z*ev[i].z + av[i].w*ev[i].w;
    }
    sse += __shfl_xor(sse, 16); sse += __shfl_xor(sse, 32);
    dae += __shfl_xor(dae, 16); dae += __shfl_xor(dae, 32);
    const float inve = 1.0f / fmaxf(sqrtf(sse), 1e-12f);
    const float def2 = 2.0f * dae * inva * inve;

    // ---- 4) own-row scalars issued before the hot loop ----
    float mk = valid ? mask[gr] : 0.f;
    const float* pp = plab + gr * 3;
    float p0 = pp[0], p1 = pp[1], p2 = pp[2];
    int lb = 0; float bst = p0;
    if (p1 > bst) { bst = p1; lb = 1; }              // first-max = argmax
    if (p2 > bst) { lb = 2; }

    __syncthreads();   // drains glds -> qt_lds ready (compiler emits vmcnt(0))

    // ---- 5) 24-tile fp8 MFMA loop; B from LDS (2 lanes/bank = free) ----
    float S1[4] = {0.f, 0.f, 0.f, 0.f};

    #pragma unroll
    for (int nt = 0; nt < 23; ++nt) {
        long b0 = (long)qt_lds[nt * 256 +       l];
        long b1 = (long)qt_lds[nt * 256 +  64 + l];
        long b2 = (long)qt_lds[nt * 256 + 128 + l];
        long b3 = (long)qt_lds[nt * 256 + 192 + l];
        f32x4 acc = {0.f, 0.f, 0.f, 0.f};
        acc = __builtin_amdgcn_mfma_f32_16x16x32_fp8_fp8(af[0], b0, acc, 0, 0, 0);
        acc = __builtin_amdgcn_mfma_f32_16x16x32_fp8_fp8(af[1], b1, acc, 0, 0, 0);
        acc = __builtin_amdgcn_mfma_f32_16x16x32_fp8_fp8(af[2], b2, acc, 0, 0, 0);
        acc = __builtin_amdgcn_mfma_f32_16x16x32_fp8_fp8(af[3], b3, acc, 0, 0, 0);
        #pragma unroll
        for (int r = 0; r < 4; ++r)
            S1[r] += __expf(acc[r]);
    }

    // tile 23: cols 368..374 real (lr<7); lanes lr=7..9 hold S2 per class
    f32x4 a23 = {0.f, 0.f, 0.f, 0.f};
    {
        long b0 = (long)qt_lds[23 * 256 +       l];
        long b1 = (long)qt_lds[23 * 256 +  64 + l];
        long b2 = (long)qt_lds[23 * 256 + 128 + l];
        long b3 = (long)qt_lds[23 * 256 + 192 + l];
        a23 = __builtin_amdgcn_mfma_f32_16x16x32_fp8_fp8(af[0], b0, a23, 0, 0, 0);
        a23 = __builtin_amdgcn_mfma_f32_16x16x32_fp8_fp8(af[1], b1, a23, 0, 0, 0);
        a23 = __builtin_amdgcn_mfma_f32_16x16x32_fp8_fp8(af[2], b2, a23, 0, 0, 0);
        a23 = __builtin_amdgcn_mfma_f32_16x16x32_fp8_fp8(af[3], b3, a23, 0, 0, 0);
        if (lr < 7) {
            #pragma unroll
            for (int r = 0; r < 4; ++r)
                S1[r] += __expf(a23[r]);
        }
    }

    // ---- 6) reduce S1 over the 16 column lanes ----
    #pragma unroll
    for (int r = 0; r < 4; ++r) {
        S1[r] += __shfl_xor(S1[r], 1);
        S1[r] += __shfl_xor(S1[r], 2);
        S1[r] += __shfl_xor(S1[r], 4);
        S1[r] += __shfl_xor(S1[r], 8);
    }

    // ---- 7) epilogue: S2 via variable-lane shuffle from tile-23 acc ----
    float c = 0.f;
    #pragma unroll
    for (int r = 0; r < 4; ++r) {
        const int m   = seg * 4 + r;                 // output row index in wave
        const int lbm = __shfl(lb, m);               // label of row m
        const float S2 = __shfl(a23[r], (l & 48) + 7 + lbm);  // C[m][375+lbm]
        const float d2 = __shfl(def2, m);
        const float mm = __shfl(mk, m);
        const float denom = __expf(d2) + S1[r];      // exactly 375 real cols
        const float per = __logf(denom) - (S2 + d2) * INV126;
        if (lr == 0) c += mm * per;
    }
    c += __shfl_xor(c, 16);
    c += __shfl_xor(c, 32);
    if (l == 0) s_red[w] = c;
    __syncthreads();
    if (w == 0) {
        float v = (l < 8) ? s_red[l] : 0.f;
        v += __shfl_xor(v, 1); v += __shfl_xor(v, 2); v += __shfl_xor(v, 4);
        if (l == 0) partial[blockIdx.x] = v;
    }
}

// ---- finish: deterministic tree reduce ----
__global__ void pgc_finish(const float* __restrict__ partial,
                           float* __restrict__ out, int n, float invB)
{
    __shared__ float r[4];
    const int tid = threadIdx.x;
    float s = 0.f;
    for (int i = tid; i < n; i += 256) s += partial[i];
    s += __shfl_xor(s, 1);  s += __shfl_xor(s, 2);
    s += __shfl_xor(s, 4);  s += __shfl_xor(s, 8);
    s += __shfl_xor(s, 16); s += __shfl_xor(s, 32);
    if ((tid & 63) == 0) r[tid >> 6] = s;
    __syncthreads();
    if (tid == 0) out[0] = (r[0] + r[1] + r[2] + r[3]) * invB;
}

extern "C" void kernel_launch(void* const* d_in, const int* in_sizes, int n_in,
                              void* d_out, int out_size, void* d_ws, size_t ws_size,
                              hipStream_t stream)
{
    const float* act   = (const float*)d_in[0];
    const float* ema   = (const float*)d_in[1];
    const float* plab  = (const float*)d_in[2];
    const float* mask  = (const float*)d_in[3];
    const float* queue = (const float*)d_in[4];
    float* out = (float*)d_out;

    const int B = in_sizes[0] / D;

    unsigned long long* qt = (unsigned long long*)d_ws;
    float* partial = (float*)((char*)d_ws + QT_BYTES);

    pgc_prep<<<24, 256, 0, stream>>>(queue, qt);
    pgc_prep_qsum<<<3, 128, 0, stream>>>(queue, (unsigned char*)d_ws);

    const int grid = (B + 127) / 128;        // 1024 for B=131072
    pgc_main<<<grid, 512, 0, stream>>>(act, ema, plab, mask, qt, partial, B);

    pgc_finish<<<1, 256, 0, stream>>>(partial, out, grid, 1.0f / (float)B);
}

// Round 16
// 46.579 us; speedup vs baseline: 1.2108x; 1.2108x over previous
//
#include <hip/hip_runtime.h>
#include <math.h>

// PseudoGroupContrast — qt-in-LDS + forced-wide load batch (sched_barrier).
//
//   prep:   queue fp32 -> fp8 e4m3, MFMA-fragment-tiled, in d_ws (48 KB).
//   prepQ:  per-class queue sums (fp8) into pad rows 375..377 (tile 23,
//           lr=7..9); rows 378..383 zero.
//   main:   grid B/128, block 512 (8 waves), LDS 48 KB, launch_bounds(512,4)
//           (VGPR cap 128 so 16 float4 loads stay LIVE -> 16 KB in flight
//           per wave; R8-R15 all collapsed to VGPR=40 with ~2 loads in
//           flight = serial HBM latency). Per block:
//             - 6 glds/thread stage qt -> LDS (fire-and-forget)
//             - issue act(8) + ema(8) + mask/plab loads back-to-back,
//               sched_barrier(0), then consume (compiler partial-waits)
//             - one __syncthreads (drains glds) -> qt ready
//             - 24-tile loop: 4 ds_read_b64 + 4 fp8 MFMA + 4 __expf;
//               tile 23: lr<7 -> S1, lanes 7..9 carry S2 per class
//           per = log(exp(def2)+S1) - (S2+def2)/126,  def2 = 2*f_hat.ef_hat
//   finish: deterministic reduce of 1024 block partials -> out.

#define D       128
#define NQ      375
#define QS      125
#define INV126  (1.0f/126.0f)
#define QT_BYTES 49152

typedef __attribute__((ext_vector_type(4))) float f32x4;

#if defined(__has_builtin)
#if __has_builtin(__builtin_amdgcn_cvt_pk_fp8_f32)
#define HAVE_CVT_FP8 1
#endif
#endif

#ifndef HAVE_CVT_FP8
static __device__ __forceinline__ unsigned f2e4m3_sw(float x) {
    unsigned u = __float_as_uint(x);
    unsigned s = (u >> 24) & 0x80;
    int e = (int)((u >> 23) & 0xFF);
    unsigned m = u & 0x7FFFFF;
    if (e == 0) return s;
    int te = e - 120;
    unsigned val;
    if (te >= 1) {
        unsigned keep = m >> 20;
        unsigned rest = m & 0xFFFFF;
        keep += (rest > 0x80000) || (rest == 0x80000 && (keep & 1));
        if (keep == 8) { keep = 0; te += 1; }
        val = (te >= 16) ? 0x7E : ((unsigned)(te << 3) | keep);
    } else {
        unsigned full = m | 0x800000;
        int sh = 21 - te;
        if (sh > 31) val = 0;
        else {
            unsigned keep = full >> sh;
            unsigned rem = full & ((1u << sh) - 1);
            unsigned half = 1u << (sh - 1);
            keep += (rem > half) || (rem == half && (keep & 1));
            val = keep;
        }
    }
    return s | val;
}
#endif

static __device__ __forceinline__ unsigned pk4(float4 v) {
#ifdef HAVE_CVT_FP8
    int r = __builtin_amdgcn_cvt_pk_fp8_f32(v.x, v.y, 0, false);
    r = __builtin_amdgcn_cvt_pk_fp8_f32(v.z, v.w, r, true);
    return (unsigned)r;
#else
    return f2e4m3_sw(v.x) | (f2e4m3_sw(v.y) << 8)
         | (f2e4m3_sw(v.z) << 16) | (f2e4m3_sw(v.w) << 24);
#endif
}

static __device__ __forceinline__ unsigned char pk1(float x) {
#ifdef HAVE_CVT_FP8
    return (unsigned char)(__builtin_amdgcn_cvt_pk_fp8_f32(x, x, 0, false) & 0xff);
#else
    return (unsigned char)f2e4m3_sw(x);
#endif
}

static __device__ __forceinline__ long pk8(float gs, float4 a, float4 b) {
    float4 sa = make_float4(gs * a.x, gs * a.y, gs * a.z, gs * a.w);
    float4 sb = make_float4(gs * b.x, gs * b.y, gs * b.z, gs * b.w);
    unsigned lo = pk4(sa), hi = pk4(sb);
    return (long)(((unsigned long)hi << 32) | (unsigned long)lo);
}

static __device__ __forceinline__ void glds16(const void* g, void* l) {
    __builtin_amdgcn_global_load_lds(
        (const __attribute__((address_space(1))) void*)g,
        (__attribute__((address_space(3))) void*)l, 16, 0, 0);
}

// ---- prep: queue -> fp8, fragment-tiled (rows >= 375 zeroed) ----
__global__ void pgc_prep(const float* __restrict__ queue,
                         unsigned long long* __restrict__ qt)
{
    int u = blockIdx.x * 256 + threadIdx.x;      // 0..6143
    if (u >= 6144) return;
    int l = u & 63, ks = (u >> 6) & 3, nt = u >> 8;
    int row = nt * 16 + (l & 15);
    int k0 = (l >> 4) * 32 + ks * 8;
    float4 a = make_float4(0.f, 0.f, 0.f, 0.f);
    float4 b = make_float4(0.f, 0.f, 0.f, 0.f);
    if (row < NQ) {
        const float* p = queue + row * D + k0;
        a = *(const float4*)p;
        b = *(const float4*)(p + 4);
    }
    unsigned lo = pk4(a), hi = pk4(b);
    qt[u] = ((unsigned long long)hi << 32) | (unsigned long long)lo;
}

// ---- prepQ: class sums into pad rows 375..377 ----
__global__ void pgc_prep_qsum(const float* __restrict__ queue,
                              unsigned char* __restrict__ qtb)
{
    int c = blockIdx.x;          // 0..2
    int d = threadIdx.x;         // 0..127
    float s = 0.f;
    const float* p = queue + (long)c * QS * D + d;
    for (int r = 0; r < QS; ++r) s += p[r * D];
    int lg = d >> 5, ks = (d >> 3) & 3, j = d & 7;
    int u = 23 * 256 + ks * 64 + lg * 16 + 7 + c;    // tile 23, lr = 7+c
    qtb[u * 8 + j] = pk1(s);
}

// ---- main ----
__global__ __launch_bounds__(512, 4) void pgc_main(
    const float* __restrict__ act,
    const float* __restrict__ ema,
    const float* __restrict__ plab,
    const float* __restrict__ mask,
    const unsigned long long* __restrict__ qt,
    float* __restrict__ partial,
    int B)
{
    __shared__ unsigned long long qt_lds[6144];      // 49152 B
    __shared__ float s_red[8];

    const int tid = threadIdx.x;
    const int w   = tid >> 6;      // 0..7
    const int l   = tid & 63;
    const int lr  = l & 15;        // own sample row / C col
    const int seg = l >> 4;        // k-segment / C row group
    const long rowbase = (long)blockIdx.x * 128 + w * 16;

    // ---- 1) stage qt -> LDS: 6 glds/thread, fire-and-forget ----
    #pragma unroll
    for (int i = 0; i < 6; ++i) {
        glds16((const char*)qt + i * 8192 + w * 1024 + l * 16,
               (char*)qt_lds + i * 8192 + w * 1024);
    }

    // ---- 2) issue the ENTIRE sample load batch (16 KB/wave in flight) ----
    long grow = rowbase + lr;
    const bool valid = grow < (long)B;
    const long gr = valid ? grow : (long)B - 1;

    const float4* ap = (const float4*)(act + gr * D) + seg * 8;
    const float4* ep = (const float4*)(ema + gr * D) + seg * 8;

    float4 av[8], ev[8];
    #pragma unroll
    for (int i = 0; i < 8; ++i) av[i] = ap[i];
    #pragma unroll
    for (int i = 0; i < 8; ++i) ev[i] = ep[i];

    float mk_raw = mask[gr];
    const float* pp = plab + gr * 3;
    float p0 = pp[0], p1 = pp[1], p2 = pp[2];

    __builtin_amdgcn_sched_barrier(0);   // loads stay issued ABOVE; consume below

    // ---- 3) consume act (partial vmcnt; ema/mask still in flight) ----
    float ssa = 0.f;
    #pragma unroll
    for (int i = 0; i < 8; ++i)
        ssa += av[i].x*av[i].x + av[i].y*av[i].y + av[i].z*av[i].z + av[i].w*av[i].w;
    ssa += __shfl_xor(ssa, 16); ssa += __shfl_xor(ssa, 32);
    const float inva = 1.0f / fmaxf(sqrtf(ssa), 1e-12f);
    const float gs   = 2.0f * inva;                  // fold 1/T + norm into A

    long af[4];
    #pragma unroll
    for (int ks = 0; ks < 4; ++ks)                   // k = seg*32 + ks*8 ..
        af[ks] = pk8(gs, av[2 * ks], av[2 * ks + 1]);

    // ---- 4) consume ema ----
    float sse = 0.f, dae = 0.f;
    #pragma unroll
    for (int i = 0; i < 8; ++i) {
        sse += ev[i].x*ev[i].x + ev[i].y*ev[i].y + ev[i].z*ev[i].z + ev[i].w*ev[i].w;
        dae += av[i].x*ev[i].x + av[i].y*ev[i].y + av[i].z*ev[i].z + av[i].w*ev[i].w;
    }
    sse += __shfl_xor(sse, 16); sse += __shfl_xor(sse, 32);
    dae += __shfl_xor(dae, 16); dae += __shfl_xor(dae, 32);
    const float inve = 1.0f / fmaxf(sqrtf(sse), 1e-12f);
    const float def2 = 2.0f * dae * inva * inve;

    // ---- 5) own-row scalars ----
    float mk = valid ? mk_raw : 0.f;
    int lb = 0; float bst = p0;
    if (p1 > bst) { bst = p1; lb = 1; }              // first-max = argmax
    if (p2 > bst) { lb = 2; }

    __syncthreads();   // drains glds -> qt_lds ready

    // ---- 6) 24-tile fp8 MFMA loop; B from LDS (2 lanes/bank = free) ----
    float S1[4] = {0.f, 0.f, 0.f, 0.f};

    #pragma unroll
    for (int nt = 0; nt < 23; ++nt) {
        long b0 = (long)qt_lds[nt * 256 +       l];
        long b1 = (long)qt_lds[nt * 256 +  64 + l];
        long b2 = (long)qt_lds[nt * 256 + 128 + l];
        long b3 = (long)qt_lds[nt * 256 + 192 + l];
        f32x4 acc = {0.f, 0.f, 0.f, 0.f};
        acc = __builtin_amdgcn_mfma_f32_16x16x32_fp8_fp8(af[0], b0, acc, 0, 0, 0);
        acc = __builtin_amdgcn_mfma_f32_16x16x32_fp8_fp8(af[1], b1, acc, 0, 0, 0);
        acc = __builtin_amdgcn_mfma_f32_16x16x32_fp8_fp8(af[2], b2, acc, 0, 0, 0);
        acc = __builtin_amdgcn_mfma_f32_16x16x32_fp8_fp8(af[3], b3, acc, 0, 0, 0);
        #pragma unroll
        for (int r = 0; r < 4; ++r)
            S1[r] += __expf(acc[r]);
    }

    // tile 23: cols 368..374 real (lr<7); lanes lr=7..9 hold S2 per class
    f32x4 a23 = {0.f, 0.f, 0.f, 0.f};
    {
        long b0 = (long)qt_lds[23 * 256 +       l];
        long b1 = (long)qt_lds[23 * 256 +  64 + l];
        long b2 = (long)qt_lds[23 * 256 + 128 + l];
        long b3 = (long)qt_lds[23 * 256 + 192 + l];
        a23 = __builtin_amdgcn_mfma_f32_16x16x32_fp8_fp8(af[0], b0, a23, 0, 0, 0);
        a23 = __builtin_amdgcn_mfma_f32_16x16x32_fp8_fp8(af[1], b1, a23, 0, 0, 0);
        a23 = __builtin_amdgcn_mfma_f32_16x16x32_fp8_fp8(af[2], b2, a23, 0, 0, 0);
        a23 = __builtin_amdgcn_mfma_f32_16x16x32_fp8_fp8(af[3], b3, a23, 0, 0, 0);
        if (lr < 7) {
            #pragma unroll
            for (int r = 0; r < 4; ++r)
                S1[r] += __expf(a23[r]);
        }
    }

    // ---- 7) reduce S1 over the 16 column lanes ----
    #pragma unroll
    for (int r = 0; r < 4; ++r) {
        S1[r] += __shfl_xor(S1[r], 1);
        S1[r] += __shfl_xor(S1[r], 2);
        S1[r] += __shfl_xor(S1[r], 4);
        S1[r] += __shfl_xor(S1[r], 8);
    }

    // ---- 8) epilogue: S2 via variable-lane shuffle from tile-23 acc ----
    float c = 0.f;
    #pragma unroll
    for (int r = 0; r < 4; ++r) {
        const int m   = seg * 4 + r;                 // output row index in wave
        const int lbm = __shfl(lb, m);               // label of row m
        const float S2 = __shfl(a23[r], (l & 48) + 7 + lbm);  // C[m][375+lbm]
        const float d2 = __shfl(def2, m);
        const float mm = __shfl(mk, m);
        const float denom = __expf(d2) + S1[r];      // exactly 375 real cols
        const float per = __logf(denom) - (S2 + d2) * INV126;
        if (lr == 0) c += mm * per;
    }
    c += __shfl_xor(c, 16);
    c += __shfl_xor(c, 32);
    if (l == 0) s_red[w] = c;
    __syncthreads();
    if (w == 0) {
        float v = (l < 8) ? s_red[l] : 0.f;
        v += __shfl_xor(v, 1); v += __shfl_xor(v, 2); v += __shfl_xor(v, 4);
        if (l == 0) partial[blockIdx.x] = v;
    }
}

// ---- finish: deterministic tree reduce ----
__global__ void pgc_finish(const float* __restrict__ partial,
                           float* __restrict__ out, int n, float invB)
{
    __shared__ float r[4];
    const int tid = threadIdx.x;
    float s = 0.f;
    for (int i = tid; i < n; i += 256) s += partial[i];
    s += __shfl_xor(s, 1);  s += __shfl_xor(s, 2);
    s += __shfl_xor(s, 4);  s += __shfl_xor(s, 8);
    s += __shfl_xor(s, 16); s += __shfl_xor(s, 32);
    if ((tid & 63) == 0) r[tid >> 6] = s;
    __syncthreads();
    if (tid == 0) out[0] = (r[0] + r[1] + r[2] + r[3]) * invB;
}

extern "C" void kernel_launch(void* const* d_in, const int* in_sizes, int n_in,
                              void* d_out, int out_size, void* d_ws, size_t ws_size,
                              hipStream_t stream)
{
    const float* act   = (const float*)d_in[0];
    const float* ema   = (const float*)d_in[1];
    const float* plab  = (const float*)d_in[2];
    const float* mask  = (const float*)d_in[3];
    const float* queue = (const float*)d_in[4];
    float* out = (float*)d_out;

    const int B = in_sizes[0] / D;

    unsigned long long* qt = (unsigned long long*)d_ws;
    float* partial = (float*)((char*)d_ws + QT_BYTES);

    pgc_prep<<<24, 256, 0, stream>>>(queue, qt);
    pgc_prep_qsum<<<3, 128, 0, stream>>>(queue, (unsigned char*)d_ws);

    const int grid = (B + 127) / 128;        // 1024 for B=131072
    pgc_main<<<grid, 512, 0, stream>>>(act, ema, plab, mask, qt, partial, B);

    pgc_finish<<<1, 256, 0, stream>>>(partial, out, grid, 1.0f / (float)B);
}